// Round 7
// baseline (31.097 us; speedup 1.0000x reference)
//
#include <hip/hip_runtime.h>

// PairwiseLoss: weighted 2-class cross-entropy + top-1 accuracy over all
// probe×gallery pairs.
//   labels[i,j] = (tp[i]==tg[j]); logits[i,j,:] = cls_encode[i,j,0:2]
//   loss = sum(w*nll)/sum(w),  w = label ? 1 : 1/4095
//   prec = 100 * mean(argmax(logits)==label)
//
// R1: libm softplus, predicated -> VALU-bound, 116 us.
// R2: __expf/__logf branch-free softplus -> 33 us.
// R3 FAILED: fused last-block ticket w/ __threadfence -> per-block L2
//     writebacks (non-coherent per-XCD L2) -> 250 us. Reverted.
// R4: hoisted loads above barrier -> 31.7 us (barrier drains vmcnt).
// R5: no barrier, 16-deep upfront loads -> 31.6 us (neutral: TLP suffices,
//     intra-wave pipeline depth is not the limiter).
// R6: 2 rows/block -> 30.3 us (-1.4): per-block overhead IS the slack.
// R7: 8 rows/block (512 blocks = 2/CU, whole grid resident). tg registers
//     loaded once serve 8 rows; tail reduces /4; row loop unroll x2 keeps
//     two rows' loads in flight at bounded VGPR.

constexpr int BATCH = 4096;
constexpr int RPB = 8;                      // rows per block
constexpr int NBLK = BATCH / RPB;           // 512 blocks
constexpr float W_NEG_F = 1.0f / 4095.0f;   // matches fp32 W_NEG in reference

__device__ __forceinline__ void pl_pair(float x, float y, bool lab,
                                        float& sum_all, float& sum_pos,
                                        int& pos, int& cor) {
    const float e = y - x;            // d when lab==0
    // log(1+exp(-|d|)) is label-independent since |d|=|e|
    const float t = __logf(1.f + __expf(-fabsf(e)));
    const float m = lab ? fmaxf(-e, 0.f) : fmaxf(e, 0.f);  // max(d,0)
    const float nll = m + t;
    sum_all += nll;
    sum_pos += lab ? nll : 0.f;
    pos += lab ? 1 : 0;
    cor += ((y > x) == lab) ? 1 : 0;  // argmax with first-index tie-break
}

// ---------------- kernel 1: per-8-row partials (deterministic) --------------
__global__ __launch_bounds__(256) void pl_partials(
    const float* __restrict__ logits,   // [BATCH*BATCH*2]
    const int* __restrict__ tp,         // [BATCH]
    const int* __restrict__ tg,         // [BATCH]
    double* __restrict__ part_wnll,     // [NBLK]
    int* __restrict__ part_pos,         // [NBLK]
    int* __restrict__ part_cor)         // [NBLK]
{
    const int t = threadIdx.x;
    const int row0 = RPB * blockIdx.x;
    const float4* rowp =
        reinterpret_cast<const float4*>(logits) + (size_t)row0 * (BATCH / 2);
    const int2* tg2 = reinterpret_cast<const int2*>(tg);

    // Gallery labels in registers ONCE per block (16 KB array, L2-warm),
    // reused across all 8 rows. No LDS, no barrier before compute.
    const int2 g0 = tg2[t];
    const int2 g1 = tg2[t + 256];
    const int2 g2 = tg2[t + 512];
    const int2 g3 = tg2[t + 768];
    const int2 g4 = tg2[t + 1024];
    const int2 g5 = tg2[t + 1280];
    const int2 g6 = tg2[t + 1536];
    const int2 g7 = tg2[t + 1792];

    float sum_all = 0.f;   // nll over all pairs this thread sees (8 rows)
    float sum_pos = 0.f;   // nll over positive pairs only
    int pos = 0, cor = 0;

#pragma unroll 2
    for (int r = 0; r < RPB; ++r) {
        const int my = tp[row0 + r];  // wave-uniform -> scalar load
        const float4* rp = rowp + (size_t)r * (BATCH / 2);
        const float4 q0 = rp[t];
        const float4 q1 = rp[t + 256];
        const float4 q2 = rp[t + 512];
        const float4 q3 = rp[t + 768];
        const float4 q4 = rp[t + 1024];
        const float4 q5 = rp[t + 1280];
        const float4 q6 = rp[t + 1536];
        const float4 q7 = rp[t + 1792];
#define PL_CHUNK(Q, G)                                                   \
        pl_pair((Q).x, (Q).y, my == (G).x, sum_all, sum_pos, pos, cor);  \
        pl_pair((Q).z, (Q).w, my == (G).y, sum_all, sum_pos, pos, cor);
        PL_CHUNK(q0, g0) PL_CHUNK(q1, g1) PL_CHUNK(q2, g2) PL_CHUNK(q3, g3)
        PL_CHUNK(q4, g4) PL_CHUNK(q5, g5) PL_CHUNK(q6, g6) PL_CHUNK(q7, g7)
#undef PL_CHUNK
    }

    // weighted combination, then wave64 shuffle reduce (double for the sum)
    double dw = (double)W_NEG_F * (double)sum_all +
                (1.0 - (double)W_NEG_F) * (double)sum_pos;
#pragma unroll
    for (int off = 32; off > 0; off >>= 1) {
        dw += __shfl_down(dw, off);
        pos += __shfl_down(pos, off);
        cor += __shfl_down(cor, off);
    }
    __shared__ double s_dw[4];
    __shared__ int s_pos[4], s_cor[4];
    const int wave = t >> 6, lane = t & 63;
    if (lane == 0) { s_dw[wave] = dw; s_pos[wave] = pos; s_cor[wave] = cor; }
    __syncthreads();  // tail only — all loads already consumed
    if (t == 0) {
        part_wnll[blockIdx.x] = s_dw[0] + s_dw[1] + s_dw[2] + s_dw[3];
        part_pos[blockIdx.x] = s_pos[0] + s_pos[1] + s_pos[2] + s_pos[3];
        part_cor[blockIdx.x] = s_cor[0] + s_cor[1] + s_cor[2] + s_cor[3];
    }
}

// ---------------- kernel 2: fixed-order final reduce ----------------
__global__ __launch_bounds__(256) void pl_final(
    const double* __restrict__ part_wnll,
    const int* __restrict__ part_pos,
    const int* __restrict__ part_cor,
    float* __restrict__ out)            // out[0]=loss, out[1]=prec
{
    const int t = threadIdx.x;
    double dw = 0.0;
    long long pos = 0, cor = 0;
#pragma unroll
    for (int v = t; v < NBLK; v += 256) {
        dw += part_wnll[v];
        pos += (long long)part_pos[v];
        cor += (long long)part_cor[v];
    }
#pragma unroll
    for (int off = 32; off > 0; off >>= 1) {
        dw += __shfl_down(dw, off);
        pos += __shfl_down(pos, off);
        cor += __shfl_down(cor, off);
    }
    __shared__ double s_dw[4];
    __shared__ long long s_pos[4], s_cor[4];
    const int wave = t >> 6, lane = t & 63;
    if (lane == 0) { s_dw[wave] = dw; s_pos[wave] = pos; s_cor[wave] = cor; }
    __syncthreads();
    if (t == 0) {
        const double tot = s_dw[0] + s_dw[1] + s_dw[2] + s_dw[3];
        const long long P = s_pos[0] + s_pos[1] + s_pos[2] + s_pos[3];
        const long long C = s_cor[0] + s_cor[1] + s_cor[2] + s_cor[3];
        const double NP = (double)BATCH * (double)BATCH;
        // sum_w is exact given the positive count
        const double sum_w = (double)P + (NP - (double)P) * (double)W_NEG_F;
        out[0] = (float)(tot / sum_w);
        out[1] = (float)(100.0 * (double)C / NP);
    }
}

extern "C" void kernel_launch(void* const* d_in, const int* in_sizes, int n_in,
                              void* d_out, int out_size, void* d_ws, size_t ws_size,
                              hipStream_t stream) {
    const float* logits = (const float*)d_in[0];  // cls_encode [4096,4096,2] f32
    const int* tp = (const int*)d_in[1];          // tar_probe  [4096] i32
    const int* tg = (const int*)d_in[2];          // tar_gallery[4096] i32
    float* out = (float*)d_out;                   // [loss, prec]

    // workspace layout: 512 doubles | 512 ints | 512 ints  (6 KiB)
    double* part_wnll = (double*)d_ws;
    int* part_pos = (int*)((char*)d_ws + NBLK * sizeof(double));
    int* part_cor = part_pos + NBLK;

    pl_partials<<<NBLK, 256, 0, stream>>>(logits, tp, tg, part_wnll, part_pos,
                                          part_cor);
    pl_final<<<1, 256, 0, stream>>>(part_wnll, part_pos, part_cor, out);
}

// Round 8
// 30.469 us; speedup vs baseline: 1.0206x; 1.0206x over previous
//
#include <hip/hip_runtime.h>

// PairwiseLoss: weighted 2-class cross-entropy + top-1 accuracy over all
// probe×gallery pairs.
//   labels[i,j] = (tp[i]==tg[j]); logits[i,j,:] = cls_encode[i,j,0:2]
//   loss = sum(w*nll)/sum(w),  w = label ? 1 : 1/4095
//   prec = 100 * mean(argmax(logits)==label)
//
// R1: libm softplus, predicated -> VALU-bound, 116 us.
// R2: __expf/__logf branch-free softplus -> 33 us.
// R3 FAILED: fused last-block ticket w/ __threadfence -> per-block L2
//     writebacks (non-coherent per-XCD L2) -> 250 us. Reverted.
// R4: hoisted loads above barrier -> 31.7 us (barrier drains vmcnt).
// R5: no barrier, 16-deep upfront loads -> 31.6 us (neutral: TLP suffices).
// R6: 2 rows/block, 2048 blocks (~4 blocks/CU) -> 30.3 us (-1.4):
//     per-block overhead is the slack.
// R7: 8 rows/block, 512 blocks = 2 blocks/CU -> 31.1 us REGRESSION:
//     grid-starved occupancy (2 waves/SIMD) outweighed amortization.
// R8: RPB=4, 1024 blocks = exactly 4 blocks/CU (16 waves/CU @ VGPR<=128).
//     Halves tails + tg traffic vs R6 at UNCHANGED occupancy.

constexpr int BATCH = 4096;
constexpr int RPB = 4;                      // rows per block
constexpr int NBLK = BATCH / RPB;           // 1024 blocks = 4 per CU
constexpr float W_NEG_F = 1.0f / 4095.0f;   // matches fp32 W_NEG in reference

__device__ __forceinline__ void pl_pair(float x, float y, bool lab,
                                        float& sum_all, float& sum_pos,
                                        int& pos, int& cor) {
    const float e = y - x;            // d when lab==0
    // log(1+exp(-|d|)) is label-independent since |d|=|e|
    const float t = __logf(1.f + __expf(-fabsf(e)));
    const float m = lab ? fmaxf(-e, 0.f) : fmaxf(e, 0.f);  // max(d,0)
    const float nll = m + t;
    sum_all += nll;
    sum_pos += lab ? nll : 0.f;
    pos += lab ? 1 : 0;
    cor += ((y > x) == lab) ? 1 : 0;  // argmax with first-index tie-break
}

// ---------------- kernel 1: per-4-row partials (deterministic) --------------
__global__ __launch_bounds__(256) void pl_partials(
    const float* __restrict__ logits,   // [BATCH*BATCH*2]
    const int* __restrict__ tp,         // [BATCH]
    const int* __restrict__ tg,         // [BATCH]
    double* __restrict__ part_wnll,     // [NBLK]
    int* __restrict__ part_pos,         // [NBLK]
    int* __restrict__ part_cor)         // [NBLK]
{
    const int t = threadIdx.x;
    const int row0 = RPB * blockIdx.x;
    const float4* rowp =
        reinterpret_cast<const float4*>(logits) + (size_t)row0 * (BATCH / 2);
    const int2* tg2 = reinterpret_cast<const int2*>(tg);

    // Gallery labels in registers once per block (16 KB, L2-warm), reused
    // across all 4 rows. No LDS, no barrier before compute.
    const int2 g0 = tg2[t];
    const int2 g1 = tg2[t + 256];
    const int2 g2 = tg2[t + 512];
    const int2 g3 = tg2[t + 768];
    const int2 g4 = tg2[t + 1024];
    const int2 g5 = tg2[t + 1280];
    const int2 g6 = tg2[t + 1536];
    const int2 g7 = tg2[t + 1792];

    float sum_all = 0.f;   // nll over all pairs this thread sees (4 rows)
    float sum_pos = 0.f;   // nll over positive pairs only
    int pos = 0, cor = 0;

    // Two sequential halves; each half = R6's proven 2-row all-upfront body.
#define PL_CHUNK(Q, G, MY)                                               \
    pl_pair((Q).x, (Q).y, (MY) == (G).x, sum_all, sum_pos, pos, cor);    \
    pl_pair((Q).z, (Q).w, (MY) == (G).y, sum_all, sum_pos, pos, cor);
#define PL_TWO_ROWS(RA, RB)                                              \
    {                                                                     \
        const int myA = tp[row0 + (RA)];                                  \
        const int myB = tp[row0 + (RB)];                                  \
        const float4* rpA = rowp + (size_t)(RA) * (BATCH / 2);            \
        const float4* rpB = rowp + (size_t)(RB) * (BATCH / 2);            \
        const float4 a0 = rpA[t];          const float4 a1 = rpA[t + 256];\
        const float4 a2 = rpA[t + 512];    const float4 a3 = rpA[t + 768];\
        const float4 a4 = rpA[t + 1024];   const float4 a5 = rpA[t + 1280];\
        const float4 a6 = rpA[t + 1536];   const float4 a7 = rpA[t + 1792];\
        const float4 b0 = rpB[t];          const float4 b1 = rpB[t + 256];\
        const float4 b2 = rpB[t + 512];    const float4 b3 = rpB[t + 768];\
        const float4 b4 = rpB[t + 1024];   const float4 b5 = rpB[t + 1280];\
        const float4 b6 = rpB[t + 1536];   const float4 b7 = rpB[t + 1792];\
        PL_CHUNK(a0, g0, myA) PL_CHUNK(a1, g1, myA) PL_CHUNK(a2, g2, myA) \
        PL_CHUNK(a3, g3, myA) PL_CHUNK(a4, g4, myA) PL_CHUNK(a5, g5, myA) \
        PL_CHUNK(a6, g6, myA) PL_CHUNK(a7, g7, myA)                       \
        PL_CHUNK(b0, g0, myB) PL_CHUNK(b1, g1, myB) PL_CHUNK(b2, g2, myB) \
        PL_CHUNK(b3, g3, myB) PL_CHUNK(b4, g4, myB) PL_CHUNK(b5, g5, myB) \
        PL_CHUNK(b6, g6, myB) PL_CHUNK(b7, g7, myB)                       \
    }
    PL_TWO_ROWS(0, 1)
    PL_TWO_ROWS(2, 3)
#undef PL_TWO_ROWS
#undef PL_CHUNK

    // weighted combination, then wave64 shuffle reduce (double for the sum)
    double dw = (double)W_NEG_F * (double)sum_all +
                (1.0 - (double)W_NEG_F) * (double)sum_pos;
#pragma unroll
    for (int off = 32; off > 0; off >>= 1) {
        dw += __shfl_down(dw, off);
        pos += __shfl_down(pos, off);
        cor += __shfl_down(cor, off);
    }
    __shared__ double s_dw[4];
    __shared__ int s_pos[4], s_cor[4];
    const int wave = t >> 6, lane = t & 63;
    if (lane == 0) { s_dw[wave] = dw; s_pos[wave] = pos; s_cor[wave] = cor; }
    __syncthreads();  // tail only — all loads already consumed
    if (t == 0) {
        part_wnll[blockIdx.x] = s_dw[0] + s_dw[1] + s_dw[2] + s_dw[3];
        part_pos[blockIdx.x] = s_pos[0] + s_pos[1] + s_pos[2] + s_pos[3];
        part_cor[blockIdx.x] = s_cor[0] + s_cor[1] + s_cor[2] + s_cor[3];
    }
}

// ---------------- kernel 2: fixed-order final reduce ----------------
__global__ __launch_bounds__(256) void pl_final(
    const double* __restrict__ part_wnll,
    const int* __restrict__ part_pos,
    const int* __restrict__ part_cor,
    float* __restrict__ out)            // out[0]=loss, out[1]=prec
{
    const int t = threadIdx.x;
    double dw = 0.0;
    long long pos = 0, cor = 0;
#pragma unroll
    for (int v = t; v < NBLK; v += 256) {
        dw += part_wnll[v];
        pos += (long long)part_pos[v];
        cor += (long long)part_cor[v];
    }
#pragma unroll
    for (int off = 32; off > 0; off >>= 1) {
        dw += __shfl_down(dw, off);
        pos += __shfl_down(pos, off);
        cor += __shfl_down(cor, off);
    }
    __shared__ double s_dw[4];
    __shared__ long long s_pos[4], s_cor[4];
    const int wave = t >> 6, lane = t & 63;
    if (lane == 0) { s_dw[wave] = dw; s_pos[wave] = pos; s_cor[wave] = cor; }
    __syncthreads();
    if (t == 0) {
        const double tot = s_dw[0] + s_dw[1] + s_dw[2] + s_dw[3];
        const long long P = s_pos[0] + s_pos[1] + s_pos[2] + s_pos[3];
        const long long C = s_cor[0] + s_cor[1] + s_cor[2] + s_cor[3];
        const double NP = (double)BATCH * (double)BATCH;
        // sum_w is exact given the positive count
        const double sum_w = (double)P + (NP - (double)P) * (double)W_NEG_F;
        out[0] = (float)(tot / sum_w);
        out[1] = (float)(100.0 * (double)C / NP);
    }
}

extern "C" void kernel_launch(void* const* d_in, const int* in_sizes, int n_in,
                              void* d_out, int out_size, void* d_ws, size_t ws_size,
                              hipStream_t stream) {
    const float* logits = (const float*)d_in[0];  // cls_encode [4096,4096,2] f32
    const int* tp = (const int*)d_in[1];          // tar_probe  [4096] i32
    const int* tg = (const int*)d_in[2];          // tar_gallery[4096] i32
    float* out = (float*)d_out;                   // [loss, prec]

    // workspace layout: 1024 doubles | 1024 ints | 1024 ints  (16 KiB)
    double* part_wnll = (double*)d_ws;
    int* part_pos = (int*)((char*)d_ws + NBLK * sizeof(double));
    int* part_cor = part_pos + NBLK;

    pl_partials<<<NBLK, 256, 0, stream>>>(logits, tp, tg, part_wnll, part_pos,
                                          part_cor);
    pl_final<<<1, 256, 0, stream>>>(part_wnll, part_pos, part_cor, out);
}

// Round 10
// 27.750 us; speedup vs baseline: 1.1206x; 1.0980x over previous
//
#include <hip/hip_runtime.h>

// PairwiseLoss: weighted 2-class cross-entropy + top-1 accuracy over all
// probe×gallery pairs.
//   labels[i,j] = (tp[i]==tg[j]); logits[i,j,:] = cls_encode[i,j,0:2]
//   loss = sum(w*nll)/sum(w),  w = label ? 1 : 1/4095
//   prec = 100 * mean(argmax(logits)==label)
//
// R1: libm softplus, predicated -> VALU-bound, 116 us.
// R2: __expf/__logf branch-free softplus -> 33 us.
// R3 FAILED: fused last-block ticket w/ __threadfence -> per-block L2
//     writebacks (non-coherent per-XCD L2) -> 250 us. Reverted.
// R4: hoisted loads above barrier -> 31.7 us (barrier drains vmcnt).
// R5: no barrier, 16-deep upfront loads -> 31.6 us (neutral: TLP suffices).
// R6: 2 rows/block, 2048 blocks -> 30.3 us (best): per-block overhead was slack.
// R7: 8 rows/block, 512 blocks -> 31.1 us (grid-starved occupancy).
// R8: 4 rows/block, 1024 blocks -> 30.5 us (neutral: overhead lever exhausted).
// R9: nontemporal builtin rejected HIP_vector_type* -> compile fail.
// R10: same theory via ext_vector_type(4) alias: NT loads on the once-read
//     134 MB logit stream (skip cache allocation churn; tg stays cached).

constexpr int BATCH = 4096;
constexpr int NPART = BATCH / 2;           // 2048 blocks, 2 rows each
constexpr float W_NEG_F = 1.0f / 4095.0f;  // matches fp32 W_NEG in reference

typedef float floatx4 __attribute__((ext_vector_type(4)));

__device__ __forceinline__ void pl_pair(float x, float y, bool lab,
                                        float& sum_all, float& sum_pos,
                                        int& pos, int& cor) {
    const float e = y - x;            // d when lab==0
    // log(1+exp(-|d|)) is label-independent since |d|=|e|
    const float t = __logf(1.f + __expf(-fabsf(e)));
    const float m = lab ? fmaxf(-e, 0.f) : fmaxf(e, 0.f);  // max(d,0)
    const float nll = m + t;
    sum_all += nll;
    sum_pos += lab ? nll : 0.f;
    pos += lab ? 1 : 0;
    cor += ((y > x) == lab) ? 1 : 0;  // argmax with first-index tie-break
}

__device__ __forceinline__ floatx4 ntload4(const float* p) {
    return __builtin_nontemporal_load(reinterpret_cast<const floatx4*>(p));
}

// ---------------- kernel 1: per-2-row partials (deterministic) --------------
__global__ __launch_bounds__(256) void pl_partials(
    const float* __restrict__ logits,   // [BATCH*BATCH*2]
    const int* __restrict__ tp,         // [BATCH]
    const int* __restrict__ tg,         // [BATCH]
    double* __restrict__ part_wnll,     // [NPART]
    int* __restrict__ part_pos,         // [NPART]
    int* __restrict__ part_cor)         // [NPART]
{
    const int t = threadIdx.x;
    const int row0 = 2 * blockIdx.x;
    const float* rowA = logits + (size_t)row0 * (2 * BATCH);
    const float* rowB = rowA + 2 * BATCH;
    const int2* tg2 = reinterpret_cast<const int2*>(tg);

    // All loads upfront, named registers, no barrier before compute.
    // Gallery int2s cached (reused by all blocks); logits NON-TEMPORAL
    // (read exactly once -> skip cache allocation).
    const int2 g0 = tg2[t];
    const int2 g1 = tg2[t + 256];
    const int2 g2 = tg2[t + 512];
    const int2 g3 = tg2[t + 768];
    const int2 g4 = tg2[t + 1024];
    const int2 g5 = tg2[t + 1280];
    const int2 g6 = tg2[t + 1536];
    const int2 g7 = tg2[t + 1792];
    const floatx4 a0 = ntload4(rowA + 4 * t);
    const floatx4 a1 = ntload4(rowA + 4 * (t + 256));
    const floatx4 a2 = ntload4(rowA + 4 * (t + 512));
    const floatx4 a3 = ntload4(rowA + 4 * (t + 768));
    const floatx4 a4 = ntload4(rowA + 4 * (t + 1024));
    const floatx4 a5 = ntload4(rowA + 4 * (t + 1280));
    const floatx4 a6 = ntload4(rowA + 4 * (t + 1536));
    const floatx4 a7 = ntload4(rowA + 4 * (t + 1792));
    const floatx4 b0 = ntload4(rowB + 4 * t);
    const floatx4 b1 = ntload4(rowB + 4 * (t + 256));
    const floatx4 b2 = ntload4(rowB + 4 * (t + 512));
    const floatx4 b3 = ntload4(rowB + 4 * (t + 768));
    const floatx4 b4 = ntload4(rowB + 4 * (t + 1024));
    const floatx4 b5 = ntload4(rowB + 4 * (t + 1280));
    const floatx4 b6 = ntload4(rowB + 4 * (t + 1536));
    const floatx4 b7 = ntload4(rowB + 4 * (t + 1792));
    const int my0 = tp[row0];      // wave-uniform -> scalar loads
    const int my1 = tp[row0 + 1];

    float sum_all = 0.f;   // nll over all pairs this thread sees (both rows)
    float sum_pos = 0.f;   // nll over positive pairs only
    int pos = 0, cor = 0;

#define PL_CHUNK(Q, G, MY)                                                   \
    pl_pair((Q).x, (Q).y, (MY) == (G).x, sum_all, sum_pos, pos, cor);        \
    pl_pair((Q).z, (Q).w, (MY) == (G).y, sum_all, sum_pos, pos, cor);
    PL_CHUNK(a0, g0, my0) PL_CHUNK(a1, g1, my0) PL_CHUNK(a2, g2, my0)
    PL_CHUNK(a3, g3, my0) PL_CHUNK(a4, g4, my0) PL_CHUNK(a5, g5, my0)
    PL_CHUNK(a6, g6, my0) PL_CHUNK(a7, g7, my0)
    PL_CHUNK(b0, g0, my1) PL_CHUNK(b1, g1, my1) PL_CHUNK(b2, g2, my1)
    PL_CHUNK(b3, g3, my1) PL_CHUNK(b4, g4, my1) PL_CHUNK(b5, g5, my1)
    PL_CHUNK(b6, g6, my1) PL_CHUNK(b7, g7, my1)
#undef PL_CHUNK

    // weighted combination, then wave64 shuffle reduce (double for the sum)
    double dw = (double)W_NEG_F * (double)sum_all +
                (1.0 - (double)W_NEG_F) * (double)sum_pos;
#pragma unroll
    for (int off = 32; off > 0; off >>= 1) {
        dw += __shfl_down(dw, off);
        pos += __shfl_down(pos, off);
        cor += __shfl_down(cor, off);
    }
    __shared__ double s_dw[4];
    __shared__ int s_pos[4], s_cor[4];
    const int wave = t >> 6, lane = t & 63;
    if (lane == 0) { s_dw[wave] = dw; s_pos[wave] = pos; s_cor[wave] = cor; }
    __syncthreads();  // tail only — all loads already consumed
    if (t == 0) {
        part_wnll[blockIdx.x] = s_dw[0] + s_dw[1] + s_dw[2] + s_dw[3];
        part_pos[blockIdx.x] = s_pos[0] + s_pos[1] + s_pos[2] + s_pos[3];
        part_cor[blockIdx.x] = s_cor[0] + s_cor[1] + s_cor[2] + s_cor[3];
    }
}

// ---------------- kernel 2: fixed-order final reduce ----------------
__global__ __launch_bounds__(256) void pl_final(
    const double* __restrict__ part_wnll,
    const int* __restrict__ part_pos,
    const int* __restrict__ part_cor,
    float* __restrict__ out)            // out[0]=loss, out[1]=prec
{
    const int t = threadIdx.x;
    double dw = 0.0;
    long long pos = 0, cor = 0;
#pragma unroll
    for (int v = t; v < NPART; v += 256) {
        dw += part_wnll[v];
        pos += (long long)part_pos[v];
        cor += (long long)part_cor[v];
    }
#pragma unroll
    for (int off = 32; off > 0; off >>= 1) {
        dw += __shfl_down(dw, off);
        pos += __shfl_down(pos, off);
        cor += __shfl_down(cor, off);
    }
    __shared__ double s_dw[4];
    __shared__ long long s_pos[4], s_cor[4];
    const int wave = t >> 6, lane = t & 63;
    if (lane == 0) { s_dw[wave] = dw; s_pos[wave] = pos; s_cor[wave] = cor; }
    __syncthreads();
    if (t == 0) {
        const double tot = s_dw[0] + s_dw[1] + s_dw[2] + s_dw[3];
        const long long P = s_pos[0] + s_pos[1] + s_pos[2] + s_pos[3];
        const long long C = s_cor[0] + s_cor[1] + s_cor[2] + s_cor[3];
        const double NP = (double)BATCH * (double)BATCH;
        // sum_w is exact given the positive count
        const double sum_w = (double)P + (NP - (double)P) * (double)W_NEG_F;
        out[0] = (float)(tot / sum_w);
        out[1] = (float)(100.0 * (double)C / NP);
    }
}

extern "C" void kernel_launch(void* const* d_in, const int* in_sizes, int n_in,
                              void* d_out, int out_size, void* d_ws, size_t ws_size,
                              hipStream_t stream) {
    const float* logits = (const float*)d_in[0];  // cls_encode [4096,4096,2] f32
    const int* tp = (const int*)d_in[1];          // tar_probe  [4096] i32
    const int* tg = (const int*)d_in[2];          // tar_gallery[4096] i32
    float* out = (float*)d_out;                   // [loss, prec]

    // workspace layout: 2048 doubles | 2048 ints | 2048 ints  (24 KiB)
    double* part_wnll = (double*)d_ws;
    int* part_pos = (int*)((char*)d_ws + NPART * sizeof(double));
    int* part_cor = part_pos + NPART;

    pl_partials<<<NPART, 256, 0, stream>>>(logits, tp, tg, part_wnll, part_pos,
                                           part_cor);
    pl_final<<<1, 256, 0, stream>>>(part_wnll, part_pos, part_cor, out);
}